// Round 8
// baseline (113.814 us; speedup 1.0000x reference)
//
#include <hip/hip_runtime.h>

// Problem constants (from reference)
#define QQ 16
#define NQ 128
#define HH 256
#define P5 1024   // 4^5
#define LOG2E   1.44269504088896340f
#define K2LOG2E 2.88539008177792681f  // 2*log2(e)
#define RPT 7    // rows per lane in main (448 rows/block -> 224 blocks <= 256 CUs)

// Raw v_exp_f32 (1 ulp, flush-denorm): avoids the __ocml_exp2_f32 wrapper
// (~5 extra VALU insts of denormal handling per call). Verified win in R7.
__device__ __forceinline__ float fast_exp2(float x) {
  return __builtin_amdgcn_exp2f(x);
}

// ---------------------------------------------------------------------------
// Block-wide sum over 256 threads (4 waves). All threads return the total.
// ---------------------------------------------------------------------------
__device__ __forceinline__ float block_sum256(float v, float* red, int t) {
#pragma unroll
  for (int o = 32; o > 0; o >>= 1) v += __shfl_down(v, o, 64);
  if ((t & 63) == 0) red[t >> 6] = v;
  __syncthreads();
  float r = red[0] + red[1] + red[2] + red[3];
  __syncthreads();
  return r;
}

// ---------------------------------------------------------------------------
// Prep kernel — 256 blocks x 256 threads (unchanged from R7; ~3 us).
// Output (SoA, constants FOLDED so main's inner loop is minimal):
//   ws[       h] = K2LOG2E * Wx1[0][h]
//   ws[ 256 + h] = K2LOG2E * Wx1[1][h]
//   ws[ 512 + h] = K2LOG2E * Wx1[2][h]
//   ws[ 768 + h] = K2LOG2E * bx1[h]
//   ws[1024 + h] = -2 * w2r[h]
//   ws[1280]     = b2r = dot(bx2, rhs)
// ---------------------------------------------------------------------------
__global__ __launch_bounds__(256) void prep_kernel(
    const float* __restrict__ eq,
    const float* __restrict__ q0, const float* __restrict__ q1,
    const float* __restrict__ q2, const float* __restrict__ q3,
    const float* __restrict__ q4,
    const float* __restrict__ Wx1, const float* __restrict__ bx1,
    const float* __restrict__ Wx2, const float* __restrict__ bx2,
    const float* __restrict__ Wq0, const float* __restrict__ bq0,
    const float* __restrict__ Wq1, const float* __restrict__ bq1,
    const float* __restrict__ Wq2, const float* __restrict__ bq2,
    const float* __restrict__ Wq3, const float* __restrict__ bq3,
    const float* __restrict__ Wq4, const float* __restrict__ bq4,
    float* __restrict__ ws) {
  __shared__ float sS[5][64];
  __shared__ float sRhs[P5];
  __shared__ float sPart[4][10];
  __shared__ float sAB[10];
  __shared__ float red[4];

  const int t = threadIdx.x;
  const int hb = blockIdx.x;
  const float c = -eq[0] * LOG2E;  // y = exp(-x^2*eq) = exp2(x^2 * c)

  const float* qs[5]  = {q0, q1, q2, q3, q4};
  const float* Wqs[5] = {Wq0, Wq1, Wq2, Wq3, Wq4};
  const float* bqs[5] = {bq0, bq1, bq2, bq3, bq4};

  // A_i = sum_r y*qx (v[2i]), B_i = sum_r y (v[2i+1])
  float v[10];
#pragma unroll
  for (int i = 0; i < 5; ++i) {
    float a = 0.f, b = 0.f;
    if (t < NQ) {
      float x = qs[i][t];
      float y = fast_exp2(x * x * c);
      a = y * x;
      b = y;
    }
    v[2 * i] = a;
    v[2 * i + 1] = b;
  }
#pragma unroll
  for (int k = 0; k < 10; ++k) {
    float s = v[k];
#pragma unroll
    for (int o = 32; o > 0; o >>= 1) s += __shfl_down(s, o, 64);
    if ((t & 63) == 0) sPart[t >> 6][k] = s;
  }
  __syncthreads();
  if (t < 10) sAB[t] = sPart[0][t] + sPart[1][t] + sPart[2][t] + sPart[3][t];
  __syncthreads();

  // s_i[j] = Wq_i[j]*A_i + bq_i[j]*B_i   (5 x 64)
  for (int k = t; k < 5 * 64; k += 256) {
    int i = k >> 6, j = k & 63;
    sS[i][j] = Wqs[i][j] * sAB[2 * i] + bqs[i][j] * sAB[2 * i + 1];
  }
  __syncthreads();

  // rhs[idx] = sum_x s0[b,x] s1[d,x] s2[f,x] s3[m,x] s4[v,x]
  for (int idx = t; idx < P5; idx += 256) {
    int b = (idx >> 8) & 3, d = (idx >> 6) & 3, f = (idx >> 4) & 3,
        m = (idx >> 2) & 3, w = idx & 3;
    float s = 0.f;
#pragma unroll
    for (int x = 0; x < QQ; ++x)
      s += sS[0][b * QQ + x] * sS[1][d * QQ + x] * sS[2][f * QQ + x] *
           sS[3][m * QQ + x] * sS[4][w * QQ + x];
    sRhs[idx] = s;
  }
  __syncthreads();

  // w2r[hb] = dot(Wx2[hb,:], rhs)
  const float* wrow = Wx2 + hb * P5;
  float p = 0.f;
#pragma unroll
  for (int k = 0; k < 4; ++k)
    p = fmaf(wrow[t + 256 * k], sRhs[t + 256 * k], p);
  p = block_sum256(p, red, t);

  if (t == 0) {
    ws[hb]          = K2LOG2E * Wx1[hb];
    ws[HH + hb]     = K2LOG2E * Wx1[HH + hb];
    ws[2 * HH + hb] = K2LOG2E * Wx1[2 * HH + hb];
    ws[3 * HH + hb] = K2LOG2E * bx1[hb];
    ws[4 * HH + hb] = -2.0f * p;
  }

  if (hb == 0) {
    float pb = 0.f;
    for (int j = t; j < P5; j += 256) pb = fmaf(bx2[j], sRhs[j], pb);
    pb = block_sum256(pb, red, t);
    if (t == 0) ws[5 * HH] = pb;
  }
}

// ---------------------------------------------------------------------------
// Main kernel: out[i] = CONST + sum_h wr'[h] / (1 + exp2(x_i.w'_h + b'_h))
// wr' = -2*w2r, CONST = b2r - 0.5*Sum wr'.
//
// R8 change: LOAD BALANCE. R6/R7 used 391 blocks on 256 CUs -> 135 CUs ran
// 2 blocks while 121 ran 1 (76% effective utilization). Now R=7 rows/lane,
// 448 rows/block, 224 blocks -> every CU gets at most ONE block. Per-wave
// trans demand = 448 sigmoids x 2 trans x 8 cyc = 7.2K cyc ~= 3.0 us, which
// equals the chip-wide trans-pipe floor (51.2M trans-ops / 19.7 T/s) -- the
// binding roofline. VALU issue (6.3K cyc) and LDS table reads (80 b128)
// hide underneath; 4 waves split h (64 each), partials combined via LDS.
// ---------------------------------------------------------------------------
__global__ __launch_bounds__(256) void main_kernel(
    const float* __restrict__ input, const float* __restrict__ ws,
    float* __restrict__ out, int n) {
  __shared__ float4 qtab[HH];         // {w0,w1,w2,b} (K2LOG2E folded)
  __shared__ float4 wtab4[HH / 4];    // -2*w2r
  __shared__ float red[4];
  __shared__ float sred[4][RPT][64];  // [wave][r][lane] partials

  const int t = threadIdx.x;
  const int lane = t & 63;
  const int wv = t >> 6;

  // ---- stage table (thread t owns h = t; coalesced global reads) ----
  const float w0 = ws[t], w1 = ws[HH + t], w2 = ws[2 * HH + t];
  const float bb = ws[3 * HH + t], wr = ws[4 * HH + t];
  qtab[t] = make_float4(w0, w1, w2, bb);
  ((float*)wtab4)[t] = wr;

  // butterfly Sum wr within each wave; combine across waves via red[]
  float s = wr;
#pragma unroll
  for (int o = 32; o > 0; o >>= 1) s += __shfl_xor(s, o, 64);
  if (lane == 0) red[wv] = s;
  __syncthreads();  // covers qtab/wtab4/red
  const float CONST = fmaf(-0.5f, (red[0] + red[1]) + (red[2] + red[3]),
                           ws[5 * HH]);

  // ---- RPT rows per lane (same rows for all 4 waves; h differs) ----
  const int row0 = blockIdx.x * (RPT * 64);
  float x0[RPT], x1[RPT], x2[RPT], acc[RPT];
#pragma unroll
  for (int r = 0; r < RPT; ++r) {
    const int row = row0 + r * 64 + lane;
    x0[r] = x1[r] = x2[r] = 0.f;
    if (row < n) {
      x0[r] = input[row * 3 + 0];
      x1[r] = input[row * 3 + 1];
      x2[r] = input[row * 3 + 2];
    }
    acc[r] = 0.f;
  }

  const int hbase = wv * 64;
#pragma unroll 4
  for (int j = 0; j < 16; ++j) {
    const float4 wq = wtab4[wv * 16 + j];
    const float wrv[4] = {wq.x, wq.y, wq.z, wq.w};
#pragma unroll
    for (int u = 0; u < 4; ++u) {
      const float4 q = qtab[hbase + j * 4 + u];
#pragma unroll
      for (int r = 0; r < RPT; ++r) {
        float a = fmaf(q.z, x2[r], fmaf(q.y, x1[r], fmaf(q.x, x0[r], q.w)));
        float rc = __builtin_amdgcn_rcpf(fast_exp2(a) + 1.0f);  // inf -> 0
        acc[r] = fmaf(wrv[u], rc, acc[r]);
      }
    }
  }

  // ---- combine the 4 waves' h-partials ----
#pragma unroll
  for (int r = 0; r < RPT; ++r) sred[wv][r][lane] = acc[r];
  __syncthreads();

  for (int rr = wv; rr < RPT; rr += 4) {
    const int row = row0 + rr * 64 + lane;
    if (row < n) {
      float sum = (sred[0][rr][lane] + sred[1][rr][lane]) +
                  (sred[2][rr][lane] + sred[3][rr][lane]);
      out[row] = sum + CONST;
    }
  }
}

// ---------------------------------------------------------------------------
extern "C" void kernel_launch(void* const* d_in, const int* in_sizes, int n_in,
                              void* d_out, int out_size, void* d_ws,
                              size_t ws_size, hipStream_t stream) {
  const float* input = (const float*)d_in[0];
  const float* eq    = (const float*)d_in[1];
  const float* q0    = (const float*)d_in[2];
  const float* q1    = (const float*)d_in[3];
  const float* q2    = (const float*)d_in[4];
  const float* q3    = (const float*)d_in[5];
  const float* q4    = (const float*)d_in[6];
  const float* Wx1   = (const float*)d_in[7];
  const float* bx1   = (const float*)d_in[8];
  const float* Wx2   = (const float*)d_in[9];
  const float* bx2   = (const float*)d_in[10];
  const float* Wq0   = (const float*)d_in[11];
  const float* bq0   = (const float*)d_in[12];
  const float* Wq1   = (const float*)d_in[13];
  const float* bq1   = (const float*)d_in[14];
  const float* Wq2   = (const float*)d_in[15];
  const float* bq2   = (const float*)d_in[16];
  const float* Wq3   = (const float*)d_in[17];
  const float* bq3   = (const float*)d_in[18];
  const float* Wq4   = (const float*)d_in[19];
  const float* bq4   = (const float*)d_in[20];

  float* ws  = (float*)d_ws;
  float* out = (float*)d_out;
  const int n = in_sizes[0] / 3;  // N = 100000

  hipLaunchKernelGGL(prep_kernel, dim3(HH), dim3(256), 0, stream,
                     eq, q0, q1, q2, q3, q4, Wx1, bx1, Wx2, bx2,
                     Wq0, bq0, Wq1, bq1, Wq2, bq2, Wq3, bq3, Wq4, bq4, ws);

  const int rows_per_block = RPT * 64;  // 448
  const int blocks = (n + rows_per_block - 1) / rows_per_block;  // 224
  hipLaunchKernelGGL(main_kernel, dim3(blocks), dim3(256), 0, stream,
                     input, ws, out, n);
}

// Round 10
// 111.662 us; speedup vs baseline: 1.0193x; 1.0193x over previous
//
#include <hip/hip_runtime.h>

// Problem constants (from reference)
#define QQ 16
#define NQ 128
#define HH 256
#define P5 1024   // 4^5
#define LOG2E   1.44269504088896340f
#define K2LOG2E 2.88539008177792681f  // 2*log2(e)
#define RPT 4    // rows per lane in main (256 rows/block -> 391 blocks)

// Raw v_exp_f32 (1 ulp, flush-denorm): avoids the __ocml_exp2_f32 wrapper
// (~5 extra VALU insts of denormal handling per call). Verified win in R7.
__device__ __forceinline__ float fast_exp2(float x) {
  return __builtin_amdgcn_exp2f(x);
}

// ---------------------------------------------------------------------------
// Block-wide sum over 256 threads (4 waves). All threads return the total.
// ---------------------------------------------------------------------------
__device__ __forceinline__ float block_sum256(float v, float* red, int t) {
#pragma unroll
  for (int o = 32; o > 0; o >>= 1) v += __shfl_down(v, o, 64);
  if ((t & 63) == 0) red[t >> 6] = v;
  __syncthreads();
  float r = red[0] + red[1] + red[2] + red[3];
  __syncthreads();
  return r;
}

// ---------------------------------------------------------------------------
// Prep kernel — 256 blocks x 256 threads. Block hb redundantly builds the
// tiny rhs vector in LDS, computes w2r[hb] = dot(Wx2[hb,:], rhs) via a
// coalesced 4KB row read, writes the packed SoA table.
// R10 change: rhs inner loop factored — thread t's 4 idx (t+256b) share
// (d,f,m,v), so s1*s2*s3*s4 is hoisted per x and reused across b:
// 8 LDS reads per x instead of 20 (the DS pipe was prep's main cost).
// Output:
//   ws[       h] = K2LOG2E * Wx1[0][h]
//   ws[ 256 + h] = K2LOG2E * Wx1[1][h]
//   ws[ 512 + h] = K2LOG2E * Wx1[2][h]
//   ws[ 768 + h] = K2LOG2E * bx1[h]
//   ws[1024 + h] = -2 * w2r[h]
//   ws[1280]     = b2r = dot(bx2, rhs)
// ---------------------------------------------------------------------------
__global__ __launch_bounds__(256) void prep_kernel(
    const float* __restrict__ eq,
    const float* __restrict__ q0, const float* __restrict__ q1,
    const float* __restrict__ q2, const float* __restrict__ q3,
    const float* __restrict__ q4,
    const float* __restrict__ Wx1, const float* __restrict__ bx1,
    const float* __restrict__ Wx2, const float* __restrict__ bx2,
    const float* __restrict__ Wq0, const float* __restrict__ bq0,
    const float* __restrict__ Wq1, const float* __restrict__ bq1,
    const float* __restrict__ Wq2, const float* __restrict__ bq2,
    const float* __restrict__ Wq3, const float* __restrict__ bq3,
    const float* __restrict__ Wq4, const float* __restrict__ bq4,
    float* __restrict__ ws) {
  __shared__ float sS[5][64];
  __shared__ float sRhs[P5];
  __shared__ float sPart[4][10];
  __shared__ float sAB[10];
  __shared__ float red[4];

  const int t = threadIdx.x;
  const int hb = blockIdx.x;
  const float c = -eq[0] * LOG2E;  // y = exp(-x^2*eq) = exp2(x^2 * c)

  const float* qs[5]  = {q0, q1, q2, q3, q4};
  const float* Wqs[5] = {Wq0, Wq1, Wq2, Wq3, Wq4};
  const float* bqs[5] = {bq0, bq1, bq2, bq3, bq4};

  // A_i = sum_r y*qx (v[2i]), B_i = sum_r y (v[2i+1])
  float v[10];
#pragma unroll
  for (int i = 0; i < 5; ++i) {
    float a = 0.f, b = 0.f;
    if (t < NQ) {
      float x = qs[i][t];
      float y = fast_exp2(x * x * c);
      a = y * x;
      b = y;
    }
    v[2 * i] = a;
    v[2 * i + 1] = b;
  }
#pragma unroll
  for (int k = 0; k < 10; ++k) {
    float s = v[k];
#pragma unroll
    for (int o = 32; o > 0; o >>= 1) s += __shfl_down(s, o, 64);
    if ((t & 63) == 0) sPart[t >> 6][k] = s;
  }
  __syncthreads();
  if (t < 10) sAB[t] = sPart[0][t] + sPart[1][t] + sPart[2][t] + sPart[3][t];
  __syncthreads();

  // s_i[j] = Wq_i[j]*A_i + bq_i[j]*B_i   (5 x 64)
  for (int k = t; k < 5 * 64; k += 256) {
    int i = k >> 6, j = k & 63;
    sS[i][j] = Wqs[i][j] * sAB[2 * i] + bqs[i][j] * sAB[2 * i + 1];
  }
  __syncthreads();

  // rhs: thread t owns idx = t + 256*b (b=0..3); d,f,m,v fixed per thread.
  {
    const int d = (t >> 6) & 3, f = (t >> 4) & 3, m = (t >> 2) & 3,
              vv = t & 3;
    float s[4] = {0.f, 0.f, 0.f, 0.f};
#pragma unroll
    for (int x = 0; x < QQ; ++x) {
      const float c1 = sS[1][d * QQ + x] * sS[2][f * QQ + x];
      const float c2 = sS[3][m * QQ + x] * sS[4][vv * QQ + x];
      const float cc = c1 * c2;
#pragma unroll
      for (int b = 0; b < 4; ++b) s[b] = fmaf(sS[0][b * QQ + x], cc, s[b]);
    }
#pragma unroll
    for (int b = 0; b < 4; ++b) sRhs[b * 256 + t] = s[b];
  }
  __syncthreads();

  // w2r[hb] = dot(Wx2[hb,:], rhs)
  const float* wrow = Wx2 + hb * P5;
  float p = 0.f;
#pragma unroll
  for (int k = 0; k < 4; ++k)
    p = fmaf(wrow[t + 256 * k], sRhs[t + 256 * k], p);
  p = block_sum256(p, red, t);

  if (t == 0) {
    ws[hb]          = K2LOG2E * Wx1[hb];
    ws[HH + hb]     = K2LOG2E * Wx1[HH + hb];
    ws[2 * HH + hb] = K2LOG2E * Wx1[2 * HH + hb];
    ws[3 * HH + hb] = K2LOG2E * bx1[hb];
    ws[4 * HH + hb] = -2.0f * p;
  }

  if (hb == 0) {
    float pb = 0.f;
    for (int j = t; j < P5; j += 256) pb = fmaf(bx2[j], sRhs[j], pb);
    pb = block_sum256(pb, red, t);
    if (t == 0) ws[5 * HH] = pb;
  }
}

// ---------------------------------------------------------------------------
// Main kernel: out[i] = CONST + sum_h wr'[h] / (1 + exp2(x_i.w'_h + b'_h))
// wr' = -2*w2r, CONST = b2r - 0.5*Sum wr'.
//
// R10 change: 512-thread blocks, EIGHT waves split h (32 each), same 391
// blocks / 256 rows / R=4. Total work per CU is unchanged, but waves/SIMD
// goes 1.53 -> 3.05, so one wave's VALU hides another's trans latency
// (R7 measured ~= the serial sum of pipes; with 3 waves the binding pipe
// is trans at ~2.6us). LDS table traffic per CU unchanged (same
// reads-per-h-per-row). Cross-wave partials combined once through LDS.
// ---------------------------------------------------------------------------
__global__ __launch_bounds__(512) void main_kernel(
    const float* __restrict__ input, const float* __restrict__ ws,
    float* __restrict__ out, int n) {
  __shared__ float4 qtab[HH];         // {w0,w1,w2,b} (K2LOG2E folded)
  __shared__ float4 wtab4[HH / 4];    // -2*w2r
  __shared__ float red[4];
  __shared__ float sred[8][RPT][64];  // [wave][r][lane] partials

  const int t = threadIdx.x;   // 0..511
  const int lane = t & 63;
  const int wv = t >> 6;       // 0..7

  // ---- stage table (threads 0..255 own h = t; coalesced global reads) ----
  if (t < HH) {
    const float w0 = ws[t], w1 = ws[HH + t], w2 = ws[2 * HH + t];
    const float bb = ws[3 * HH + t], wr = ws[4 * HH + t];
    qtab[t] = make_float4(w0, w1, w2, bb);
    ((float*)wtab4)[t] = wr;
    // butterfly Sum wr within waves 0-3; combine via red[]
    float s = wr;
#pragma unroll
    for (int o = 32; o > 0; o >>= 1) s += __shfl_xor(s, o, 64);
    if (lane == 0) red[wv] = s;
  }
  __syncthreads();  // covers qtab/wtab4/red
  const float CONST = fmaf(-0.5f, (red[0] + red[1]) + (red[2] + red[3]),
                           ws[5 * HH]);

  // ---- RPT rows per lane (same 256 rows for all 8 waves; h differs) ----
  const int row0 = blockIdx.x * (RPT * 64);
  float x0[RPT], x1[RPT], x2[RPT], acc[RPT];
#pragma unroll
  for (int r = 0; r < RPT; ++r) {
    const int row = row0 + r * 64 + lane;
    x0[r] = x1[r] = x2[r] = 0.f;
    if (row < n) {
      x0[r] = input[row * 3 + 0];
      x1[r] = input[row * 3 + 1];
      x2[r] = input[row * 3 + 2];
    }
    acc[r] = 0.f;
  }

  const int hbase = wv * 32;  // each wave owns 32 h
#pragma unroll 4
  for (int j = 0; j < 8; ++j) {
    const float4 wq = wtab4[wv * 8 + j];
    const float wrv[4] = {wq.x, wq.y, wq.z, wq.w};
#pragma unroll
    for (int u = 0; u < 4; ++u) {
      const float4 q = qtab[hbase + j * 4 + u];
#pragma unroll
      for (int r = 0; r < RPT; ++r) {
        float a = fmaf(q.z, x2[r], fmaf(q.y, x1[r], fmaf(q.x, x0[r], q.w)));
        float rc = __builtin_amdgcn_rcpf(fast_exp2(a) + 1.0f);  // inf -> 0
        acc[r] = fmaf(wrv[u], rc, acc[r]);
      }
    }
  }

  // ---- combine the 8 waves' h-partials ----
#pragma unroll
  for (int r = 0; r < RPT; ++r) sred[wv][r][lane] = acc[r];
  __syncthreads();

  if (t < 256) {
    const int rr = t >> 6;  // 0..3 == RPT row groups
    const int row = row0 + rr * 64 + lane;
    if (row < n) {
      float sum = ((sred[0][rr][lane] + sred[1][rr][lane]) +
                   (sred[2][rr][lane] + sred[3][rr][lane])) +
                  ((sred[4][rr][lane] + sred[5][rr][lane]) +
                   (sred[6][rr][lane] + sred[7][rr][lane]));
      out[row] = sum + CONST;
    }
  }
}

// ---------------------------------------------------------------------------
extern "C" void kernel_launch(void* const* d_in, const int* in_sizes, int n_in,
                              void* d_out, int out_size, void* d_ws,
                              size_t ws_size, hipStream_t stream) {
  const float* input = (const float*)d_in[0];
  const float* eq    = (const float*)d_in[1];
  const float* q0    = (const float*)d_in[2];
  const float* q1    = (const float*)d_in[3];
  const float* q2    = (const float*)d_in[4];
  const float* q3    = (const float*)d_in[5];
  const float* q4    = (const float*)d_in[6];
  const float* Wx1   = (const float*)d_in[7];
  const float* bx1   = (const float*)d_in[8];
  const float* Wx2   = (const float*)d_in[9];
  const float* bx2   = (const float*)d_in[10];
  const float* Wq0   = (const float*)d_in[11];
  const float* bq0   = (const float*)d_in[12];
  const float* Wq1   = (const float*)d_in[13];
  const float* bq1   = (const float*)d_in[14];
  const float* Wq2   = (const float*)d_in[15];
  const float* bq2   = (const float*)d_in[16];
  const float* Wq3   = (const float*)d_in[17];
  const float* bq3   = (const float*)d_in[18];
  const float* Wq4   = (const float*)d_in[19];
  const float* bq4   = (const float*)d_in[20];

  float* ws  = (float*)d_ws;
  float* out = (float*)d_out;
  const int n = in_sizes[0] / 3;  // N = 100000

  hipLaunchKernelGGL(prep_kernel, dim3(HH), dim3(256), 0, stream,
                     eq, q0, q1, q2, q3, q4, Wx1, bx1, Wx2, bx2,
                     Wq0, bq0, Wq1, bq1, Wq2, bq2, Wq3, bq3, Wq4, bq4, ws);

  const int rows_per_block = RPT * 64;  // 256
  const int blocks = (n + rows_per_block - 1) / rows_per_block;  // 391
  hipLaunchKernelGGL(main_kernel, dim3(blocks), dim3(512), 0, stream,
                     input, ws, out, n);
}